// Round 1
// baseline (436.743 us; speedup 1.0000x reference)
//
#include <hip/hip_runtime.h>

// Problem constants (match reference setup_inputs)
#define B_   1024
#define C_   200
#define L_   3
#define DIM_ 512
#define S_   (C_ + 1)   // 201 output rows per batch

// One block per (b, s) output row; 128 threads * float4 = 512 floats of d.
__global__ __launch_bounds__(128) void GSE_84722524880902_kernel(
    const float* __restrict__ x,        // [B, C]
    const float* __restrict__ W,        // [C, L, DIM]
    const float* __restrict__ cls_tok,  // [1, 1, DIM]
    const float* __restrict__ pe,       // [C+1, DIM]
    float* __restrict__ out)            // [B, C+1, DIM]
{
    const int bs = blockIdx.x;          // b * S_ + s
    const int b  = bs / S_;
    const int s  = bs - b * S_;
    const int d  = threadIdx.x << 2;    // float4 lane offset in [0, 512)

    const float4 pev = *(const float4*)(pe + s * DIM_ + d);
    float4 r;

    if (s == 0) {
        // cls row: cls_token + pe[0]
        const float4 cv = *(const float4*)(cls_tok + d);
        r.x = cv.x + pev.x;
        r.y = cv.y + pev.y;
        r.z = cv.z + pev.z;
        r.w = cv.w + pev.w;
    } else {
        const int c  = s - 1;
        // edge-replicate pad: window indices clamp into [0, C-1]
        const int cm = (c > 0)      ? c - 1 : 0;
        const int cp = (c < C_ - 1) ? c + 1 : C_ - 1;

        // wave-uniform scalar loads (all lanes same address -> s_load / broadcast)
        const float w0 = x[b * C_ + cm];
        const float w1 = x[b * C_ + c];
        const float w2 = x[b * C_ + cp];

        const float* wrow = W + c * (L_ * DIM_) + d;
        const float4 a0 = *(const float4*)(wrow + 0 * DIM_);
        const float4 a1 = *(const float4*)(wrow + 1 * DIM_);
        const float4 a2 = *(const float4*)(wrow + 2 * DIM_);

        r.x = fmaf(w0, a0.x, fmaf(w1, a1.x, fmaf(w2, a2.x, pev.x)));
        r.y = fmaf(w0, a0.y, fmaf(w1, a1.y, fmaf(w2, a2.y, pev.y)));
        r.z = fmaf(w0, a0.z, fmaf(w1, a1.z, fmaf(w2, a2.z, pev.z)));
        r.w = fmaf(w0, a0.w, fmaf(w1, a1.w, fmaf(w2, a2.w, pev.w)));
    }

    *(float4*)(out + bs * DIM_ + d) = r;
}

extern "C" void kernel_launch(void* const* d_in, const int* in_sizes, int n_in,
                              void* d_out, int out_size, void* d_ws, size_t ws_size,
                              hipStream_t stream) {
    const float* x       = (const float*)d_in[0];   // [B, C]
    const float* W       = (const float*)d_in[1];   // [C, L, DIM]
    const float* cls_tok = (const float*)d_in[2];   // [1, 1, DIM]
    const float* pe      = (const float*)d_in[3];   // [C+1, DIM]
    float* out           = (float*)d_out;           // [B, C+1, DIM]

    const int grid = B_ * S_;                       // 205824 blocks
    GSE_84722524880902_kernel<<<grid, 128, 0, stream>>>(x, W, cls_tok, pe, out);
}